// Round 1
// baseline (212.031 us; speedup 1.0000x reference)
//
#include <hip/hip_runtime.h>

#define NB   8
#define NC   64
#define H    128
#define W    128
#define TILE 16

typedef __attribute__((ext_vector_type(8))) short short8;
typedef __attribute__((ext_vector_type(4))) float float4_t;
typedef __attribute__((ext_vector_type(2))) float float2_t;

static __device__ __forceinline__ unsigned short f2bf(float f) {
    unsigned u = __builtin_bit_cast(unsigned, f);
    u += 0x7fffu + ((u >> 16) & 1u);   // round-to-nearest-even
    return (unsigned short)(u >> 16);
}

// ---------------- fused prep: weights (blockIdx.y==NB) + x conversion ----------------
// Weights: fold 3x3 -> per-parity 2x2, MFMA A-frag order.
// k = tap*64 + ic (tap=(i,j) at input offset (pr+i-1, pc+j-1));
// flat: (((p*8 + s)*4 + m)*64 + lane)*8 + jj,  s=tap*2+(ic>>5), m=oc>>4,
// lane=((ic>>3)&3)*16+(oc&15), jj=ic&7.  Total 128 KiB bf16.
// x: NCHW fp32 -> pixel-major channel-last bf16: xcl[((b*H + h)*W + w)*64 + ic]
__global__ __launch_bounds__(256) void prep_and_cvt(
    const float* __restrict__ x, const float* __restrict__ w,
    unsigned* __restrict__ xcl32, unsigned short* __restrict__ Aw) {
    __shared__ float t[NC][65];
    const int tid = threadIdx.x;

    if (blockIdx.y == NB) {
        // ---- weight prep path (16 useful blocks) ----
        if (blockIdx.x >= 16) return;
        int tt = blockIdx.x * 256 + tid;
        int oc = tt >> 6, ic = tt & 63;
        const float* wp = w + (oc * NC + ic) * 9;
        float wv[3][3];
#pragma unroll
        for (int kh = 0; kh < 3; ++kh)
#pragma unroll
            for (int kw = 0; kw < 3; ++kw) wv[kh][kw] = wp[kh * 3 + kw];
        float rc[2][2][3];
#pragma unroll
        for (int kw = 0; kw < 3; ++kw) {
            rc[0][0][kw] = wv[0][kw];
            rc[0][1][kw] = wv[1][kw] + wv[2][kw];
            rc[1][0][kw] = wv[0][kw] + wv[1][kw];
            rc[1][1][kw] = wv[2][kw];
        }
        int m = oc >> 4;
        int lane = ((ic >> 3) & 3) * 16 + (oc & 15);
        int jj = ic & 7;
#pragma unroll
        for (int pr = 0; pr < 2; ++pr)
#pragma unroll
            for (int pc = 0; pc < 2; ++pc) {
                int p = pr * 2 + pc;
#pragma unroll
                for (int i = 0; i < 2; ++i)
#pragma unroll
                    for (int j = 0; j < 2; ++j) {
                        float v;
                        if (pc == 0) v = (j == 0) ? rc[pr][i][0] : (rc[pr][i][1] + rc[pr][i][2]);
                        else         v = (j == 0) ? (rc[pr][i][0] + rc[pr][i][1]) : rc[pr][i][2];
                        int s = (i * 2 + j) * 2 + (ic >> 5);
                        Aw[((((size_t)(p * 8 + s) * 4 + m) * 64 + lane) * 8) + jj] = f2bf(v);
                    }
            }
        return;
    }

    // ---- x conversion path ----
    const int px0 = blockIdx.x * 64;
    const int b = blockIdx.y;
    const float* xb = x + (size_t)b * NC * H * W + px0;
    {
        const int ic4 = tid >> 6, px = tid & 63;
#pragma unroll
        for (int io = 0; io < 16; ++io) {
            int ic = io * 4 + ic4;
            t[ic][px] = xb[(size_t)ic * (H * W) + px];
        }
    }
    __syncthreads();
    {
        const int icp = tid & 31;
#pragma unroll
        for (int po = 0; po < 8; ++po) {
            int px = po * 8 + (tid >> 5);
            unsigned d = (unsigned)f2bf(t[2 * icp][px]) | ((unsigned)f2bf(t[2 * icp + 1][px]) << 16);
            xcl32[((size_t)b * (H * W) + px0 + px) * 32 + icp] = d;
        }
    }
}

// ---------------- conv: LDS-free, rolling B-window software pipeline ----------------
// grid.x = b + 8*tile (batch pinned to XCD for L2 residency of its 2 MB slice)
// grid.z = pr*2 + ocg (row parity x 32-oc group)
// wave: 4 pixel-rows x 32 oc x both col parities; acc[2][4][2] float4 = 64 VGPRs.
// launch_bounds(256,3): VGPR cap 170 so the NEXT row's 3 B-frags (Bn, 12 VGPRs)
// can stay in flight across the 8-MFMA cluster (was capped at 128 -> serialized
// {load, vmcnt(0), mfma} per t-step).
__global__ __launch_bounds__(256, 3) void upconv_mfma(
    const unsigned short* __restrict__ xcl, const unsigned short* __restrict__ Aw,
    const float* __restrict__ bias, float* __restrict__ out) {
    const int tid = threadIdx.x;
    const int wave = tid >> 6, lane = tid & 63;
    const int tcl = lane & 15, khi = lane >> 4;

    const int bx = blockIdx.x;
    const int b = bx & 7, tile = bx >> 3;
    const int tx = tile & 7, ty = tile >> 3;
    const int r0 = ty * TILE, c0 = tx * TILE;
    const int z = blockIdx.z, pr = z >> 1, ocg = z & 1;
    const bool edge = (tx == 0) | (tx == 7);

    const unsigned short* xb = xcl + (size_t)b * (H * W) * 64;
    const int laneB = tcl * 64 + khi * 8;  // shorts within a pixel-row
    const int rbase = r0 + wave * 4 + pr - 1;

    float4_t acc[2][4][2];
#pragma unroll
    for (int m = 0; m < 2; ++m)
#pragma unroll
        for (int t = 0; t < 4; ++t)
#pragma unroll
            for (int pc = 0; pc < 2; ++pc) acc[m][t][pc] = (float4_t){0.f, 0.f, 0.f, 0.f};

#pragma unroll
    for (int i = 0; i < 2; ++i) {
#pragma unroll
        for (int ich = 0; ich < 2; ++ich) {
            // hoist A-frags for this (i, ich): 8 frags = 32 VGPRs
            short8 Af[2][2][2];  // [j][pc][m]
#pragma unroll
            for (int j = 0; j < 2; ++j)
#pragma unroll
                for (int pc = 0; pc < 2; ++pc)
#pragma unroll
                    for (int m = 0; m < 2; ++m) {
                        int s = (i * 2 + j) * 2 + ich;
                        int p = pr * 2 + pc;
                        Af[j][pc][m] = *(const short8*)(
                            Aw + (((size_t)(p * 8 + s) * 4 + (ocg * 2 + m)) * 64 + lane) * 8);
                    }

            // row loader: clamped row so prefetches of invalid rows stay in-bounds
            // (their MFMAs are skipped by the wave-uniform guard below).
            auto load_row = [&](short8* B, int row) {
                int vr = row < 0 ? 0 : (row > H - 1 ? H - 1 : row);
                const unsigned short* rp = xb + (size_t)vr * (W * 64);
#pragma unroll
                for (int sh = 0; sh < 3; ++sh) {
                    if (!edge) {
                        B[sh] = *(const short8*)(rp + (c0 - 1 + sh) * 64 + laneB + ich * 32);
                    } else {
                        int gc = c0 - 1 + sh + tcl;
                        int gcc = gc < 0 ? 0 : (gc > W - 1 ? W - 1 : gc);
                        short8 v = *(const short8*)(rp + gcc * 64 + khi * 8 + ich * 32);
                        if ((unsigned)gc >= (unsigned)W) v = (short8)0;
                        B[sh] = v;
                    }
                }
            };

            short8 Bs[3];  // col shifts 0,1,2 (shift 1 shared by pc0/j1 and pc1/j0)
            load_row(Bs, rbase + 0 + i);
#pragma unroll
            for (int t = 0; t < 4; ++t) {
                short8 Bn[3];
                if (t < 3) load_row(Bn, rbase + t + 1 + i);  // prefetch next row

                const int row = rbase + t + i;
                if ((unsigned)row < (unsigned)H) {  // wave-uniform
#pragma unroll
                    for (int pc = 0; pc < 2; ++pc)
#pragma unroll
                        for (int j = 0; j < 2; ++j)
#pragma unroll
                            for (int m = 0; m < 2; ++m)
                                acc[m][t][pc] = __builtin_amdgcn_mfma_f32_16x16x32_bf16(
                                    Af[j][pc][m], Bs[pc + j], acc[m][t][pc], 0, 0, 0);
                }
                if (t < 3) { Bs[0] = Bn[0]; Bs[1] = Bn[1]; Bs[2] = Bn[2]; }
            }
        }
    }

    // ---- epilogue: +bias, nontemporal float2 stores (pure streaming output;
    // keep per-XCD L2 free for the batch's xcl slice) ----
#pragma unroll
    for (int m = 0; m < 2; ++m) {
        const int ocb = (ocg * 2 + m) * 16 + khi * 4;
        const float4_t bv = *(const float4_t*)(bias + ocb);
#pragma unroll
        for (int t = 0; t < 4; ++t) {
            const int orow = 2 * (r0 + wave * 4 + t) + pr;
#pragma unroll
            for (int reg = 0; reg < 4; ++reg) {
                float2_t v;
                v.x = acc[m][t][0][reg] + bv[reg];
                v.y = acc[m][t][1][reg] + bv[reg];
                size_t idx = (((size_t)(b * NC + ocb + reg) * 256 + orow) * 256) + 2 * (c0 + tcl);
                __builtin_nontemporal_store(v, reinterpret_cast<float2_t*>(out + idx));
            }
        }
    }
}

extern "C" void kernel_launch(void* const* d_in, const int* in_sizes, int n_in,
                              void* d_out, int out_size, void* d_ws, size_t ws_size,
                              hipStream_t stream) {
    const float* x    = (const float*)d_in[0];
    const float* wgt  = (const float*)d_in[1];
    const float* bias = (const float*)d_in[2];
    float* out = (float*)d_out;
    unsigned short* Aw  = (unsigned short*)d_ws;                                 // 128 KiB
    unsigned short* xcl = (unsigned short*)((char*)d_ws + (64 * 64 * 16) * 2);   // 16.8 MB

    prep_and_cvt<<<dim3(256, NB + 1), dim3(256), 0, stream>>>(x, wgt, (unsigned*)xcl, Aw);
    upconv_mfma<<<dim3(8 * 64, 1, 4), dim3(256), 0, stream>>>(xcl, Aw, bias, out);
}

// Round 2
// 192.077 us; speedup vs baseline: 1.1039x; 1.1039x over previous
//
#include <hip/hip_runtime.h>

#define NB   8
#define NC   64
#define H    128
#define W    128
#define TILE 16

typedef __attribute__((ext_vector_type(8))) short short8;
typedef __attribute__((ext_vector_type(4))) float float4_t;
typedef __attribute__((ext_vector_type(2))) float float2_t;

static __device__ __forceinline__ unsigned short f2bf(float f) {
    unsigned u = __builtin_bit_cast(unsigned, f);
    u += 0x7fffu + ((u >> 16) & 1u);   // round-to-nearest-even
    return (unsigned short)(u >> 16);
}

// ---------------- fused prep: weights (blockIdx.y==NB) + x conversion ----------------
// Weights: fold 3x3 -> per-parity 2x2, MFMA A-frag order.
// flat: (((p*8 + s)*4 + m)*64 + lane)*8 + jj,  s=tap*2+(ic>>5), m=oc>>4,
// lane=((ic>>3)&3)*16+(oc&15), jj=ic&7.  Total 128 KiB bf16.
// x: NCHW fp32 -> pixel-major channel-last bf16: xcl[((b*H + h)*W + w)*64 + ic]
__global__ __launch_bounds__(256) void prep_and_cvt(
    const float* __restrict__ x, const float* __restrict__ w,
    unsigned* __restrict__ xcl32, unsigned short* __restrict__ Aw) {
    __shared__ float t[NC][65];
    const int tid = threadIdx.x;

    if (blockIdx.y == NB) {
        // ---- weight prep path (16 useful blocks) ----
        if (blockIdx.x >= 16) return;
        int tt = blockIdx.x * 256 + tid;
        int oc = tt >> 6, ic = tt & 63;
        const float* wp = w + (oc * NC + ic) * 9;
        float wv[3][3];
#pragma unroll
        for (int kh = 0; kh < 3; ++kh)
#pragma unroll
            for (int kw = 0; kw < 3; ++kw) wv[kh][kw] = wp[kh * 3 + kw];
        float rc[2][2][3];
#pragma unroll
        for (int kw = 0; kw < 3; ++kw) {
            rc[0][0][kw] = wv[0][kw];
            rc[0][1][kw] = wv[1][kw] + wv[2][kw];
            rc[1][0][kw] = wv[0][kw] + wv[1][kw];
            rc[1][1][kw] = wv[2][kw];
        }
        int m = oc >> 4;
        int lane = ((ic >> 3) & 3) * 16 + (oc & 15);
        int jj = ic & 7;
#pragma unroll
        for (int pr = 0; pr < 2; ++pr)
#pragma unroll
            for (int pc = 0; pc < 2; ++pc) {
                int p = pr * 2 + pc;
#pragma unroll
                for (int i = 0; i < 2; ++i)
#pragma unroll
                    for (int j = 0; j < 2; ++j) {
                        float v;
                        if (pc == 0) v = (j == 0) ? rc[pr][i][0] : (rc[pr][i][1] + rc[pr][i][2]);
                        else         v = (j == 0) ? (rc[pr][i][0] + rc[pr][i][1]) : rc[pr][i][2];
                        int s = (i * 2 + j) * 2 + (ic >> 5);
                        Aw[((((size_t)(p * 8 + s) * 4 + m) * 64 + lane) * 8) + jj] = f2bf(v);
                    }
            }
        return;
    }

    // ---- x conversion path ----
    const int px0 = blockIdx.x * 64;
    const int b = blockIdx.y;
    const float* xb = x + (size_t)b * NC * H * W + px0;
    {
        const int ic4 = tid >> 6, px = tid & 63;
#pragma unroll
        for (int io = 0; io < 16; ++io) {
            int ic = io * 4 + ic4;
            t[ic][px] = xb[(size_t)ic * (H * W) + px];
        }
    }
    __syncthreads();
    {
        const int icp = tid & 31;
#pragma unroll
        for (int po = 0; po < 8; ++po) {
            int px = po * 8 + (tid >> 5);
            unsigned d = (unsigned)f2bf(t[2 * icp][px]) | ((unsigned)f2bf(t[2 * icp + 1][px]) << 16);
            xcl32[((size_t)b * (H * W) + px0 + px) * 32 + icp] = d;
        }
    }
}

// ---------------- conv: LDS-free, all 64 oc per block (z = row parity only) ----------------
// grid.x = b + 8*tile (batch pinned to XCD for L2 residency of its 2 MB slice)
// grid.z = pr (row parity); ALL 64 output channels per block -> B-frags loaded once
// per tile-parity instead of twice (halves xcl L2 read traffic + address issue work).
// wave: 4 pixel-rows x 64 oc x both col parities.
// acc[4][4][2] float4 = 128 VGPR; Af 16 frags = 64 VGPR; Bs/Bn 24 -> ~230 VGPR.
// launch_bounds(256,2): cap 256 VGPR, 2 blocks/CU (8 waves/CU) — enough TLP for a
// store-bound kernel with 16 MFMAs per B-set of ILP.
__global__ __launch_bounds__(256, 2) void upconv_mfma(
    const unsigned short* __restrict__ xcl, const unsigned short* __restrict__ Aw,
    const float* __restrict__ bias, float* __restrict__ out) {
    const int tid = threadIdx.x;
    const int wave = tid >> 6, lane = tid & 63;
    const int tcl = lane & 15, khi = lane >> 4;

    const int bx = blockIdx.x;
    const int b = bx & 7, tile = bx >> 3;
    const int tx = tile & 7, ty = tile >> 3;
    const int r0 = ty * TILE, c0 = tx * TILE;
    const int pr = blockIdx.z;
    const bool edge = (tx == 0) | (tx == 7);

    const unsigned short* xb = xcl + (size_t)b * (H * W) * 64;
    const int laneB = tcl * 64 + khi * 8;  // shorts within a pixel-row
    const int rbase = r0 + wave * 4 + pr - 1;

    float4_t acc[4][4][2];
#pragma unroll
    for (int m = 0; m < 4; ++m)
#pragma unroll
        for (int t = 0; t < 4; ++t)
#pragma unroll
            for (int pc = 0; pc < 2; ++pc) acc[m][t][pc] = (float4_t){0.f, 0.f, 0.f, 0.f};

#pragma unroll
    for (int i = 0; i < 2; ++i) {
#pragma unroll
        for (int ich = 0; ich < 2; ++ich) {
            // hoist A-frags for this (i, ich): 16 frags = 64 VGPRs
            short8 Af[2][2][4];  // [j][pc][m]
#pragma unroll
            for (int j = 0; j < 2; ++j)
#pragma unroll
                for (int pc = 0; pc < 2; ++pc)
#pragma unroll
                    for (int m = 0; m < 4; ++m) {
                        int s = (i * 2 + j) * 2 + ich;
                        int p = pr * 2 + pc;
                        Af[j][pc][m] = *(const short8*)(
                            Aw + (((size_t)(p * 8 + s) * 4 + m) * 64 + lane) * 8);
                    }

            // row loader: clamped row so prefetches of invalid rows stay in-bounds
            // (their MFMAs are skipped by the wave-uniform guard below).
            auto load_row = [&](short8* B, int row) {
                int vr = row < 0 ? 0 : (row > H - 1 ? H - 1 : row);
                const unsigned short* rp = xb + (size_t)vr * (W * 64);
#pragma unroll
                for (int sh = 0; sh < 3; ++sh) {
                    if (!edge) {
                        B[sh] = *(const short8*)(rp + (c0 - 1 + sh) * 64 + laneB + ich * 32);
                    } else {
                        int gc = c0 - 1 + sh + tcl;
                        int gcc = gc < 0 ? 0 : (gc > W - 1 ? W - 1 : gc);
                        short8 v = *(const short8*)(rp + gcc * 64 + khi * 8 + ich * 32);
                        if ((unsigned)gc >= (unsigned)W) v = (short8)0;
                        B[sh] = v;
                    }
                }
            };

            short8 Bs[3];  // col shifts 0,1,2 (shift 1 shared by pc0/j1 and pc1/j0)
            load_row(Bs, rbase + 0 + i);
#pragma unroll
            for (int t = 0; t < 4; ++t) {
                short8 Bn[3];
                if (t < 3) load_row(Bn, rbase + t + 1 + i);  // prefetch next row

                const int row = rbase + t + i;
                if ((unsigned)row < (unsigned)H) {  // wave-uniform
#pragma unroll
                    for (int pc = 0; pc < 2; ++pc)
#pragma unroll
                        for (int j = 0; j < 2; ++j)
#pragma unroll
                            for (int m = 0; m < 4; ++m)
                                acc[m][t][pc] = __builtin_amdgcn_mfma_f32_16x16x32_bf16(
                                    Af[j][pc][m], Bs[pc + j], acc[m][t][pc], 0, 0, 0);
                }
                if (t < 3) { Bs[0] = Bn[0]; Bs[1] = Bn[1]; Bs[2] = Bn[2]; }
            }
        }
    }

    // ---- epilogue: +bias, nontemporal float2 stores (pure streaming output;
    // keep per-XCD L2 free for the batch's xcl slice) ----
#pragma unroll
    for (int m = 0; m < 4; ++m) {
        const int ocb = m * 16 + khi * 4;
        const float4_t bv = *(const float4_t*)(bias + ocb);
#pragma unroll
        for (int t = 0; t < 4; ++t) {
            const int orow = 2 * (r0 + wave * 4 + t) + pr;
#pragma unroll
            for (int reg = 0; reg < 4; ++reg) {
                float2_t v;
                v.x = acc[m][t][0][reg] + bv[reg];
                v.y = acc[m][t][1][reg] + bv[reg];
                size_t idx = (((size_t)(b * NC + ocb + reg) * 256 + orow) * 256) + 2 * (c0 + tcl);
                __builtin_nontemporal_store(v, reinterpret_cast<float2_t*>(out + idx));
            }
        }
    }
}

extern "C" void kernel_launch(void* const* d_in, const int* in_sizes, int n_in,
                              void* d_out, int out_size, void* d_ws, size_t ws_size,
                              hipStream_t stream) {
    const float* x    = (const float*)d_in[0];
    const float* wgt  = (const float*)d_in[1];
    const float* bias = (const float*)d_in[2];
    float* out = (float*)d_out;
    unsigned short* Aw  = (unsigned short*)d_ws;                                 // 128 KiB
    unsigned short* xcl = (unsigned short*)((char*)d_ws + (64 * 64 * 16) * 2);   // 16.8 MB

    prep_and_cvt<<<dim3(256, NB + 1), dim3(256), 0, stream>>>(x, wgt, (unsigned*)xcl, Aw);
    upconv_mfma<<<dim3(8 * 64, 1, 2), dim3(256), 0, stream>>>(xcl, Aw, bias, out);
}